// Round 2
// baseline (20855.174 us; speedup 1.0000x reference)
//
#include <hip/hip_runtime.h>
#include <math.h>

// Problem constants (from reference)
#define NXD 64
#define NYD 48
#define NZD 32
#define NPT (NXD*NYD*NZD)   // 98304 points
#define PN  10              // neighbors per point
#define MF  5               // fourier modes
#define INF 33              // 3 + 2*5*3
#define H1  64
#define H2  32
#define H3  8

// LDS layout (float offsets, all 16B-aligned)
#define LW1 0        // 33*64 = 2112
#define LB1 2112     // 64
#define LW2 2176     // 64*32 = 2048
#define LB2 4224     // 32
#define LW3 4256     // 32*8 = 256
#define LB3 4512     // 8
#define LTOT 4520    // floats

__device__ __forceinline__ float gelu_exact(float v) {
    // jax.nn.gelu(approximate=False): 0.5*x*(1+erf(x/sqrt(2)))
    return 0.5f * v * (1.0f + erff(v * 0.70710678118654752f));
}

// 2 threads per point; each handles 5 of the 10 neighbors, pair-reduced by shfl.
// Weights staged in LDS, read as float4 broadcast (ds_read_b128, conflict-free).
__global__ __launch_bounds__(256) void domino_mlp_kernel(
    const float* __restrict__ x,      // (NPT, PN, 3)
    const float* __restrict__ freqs,  // (MF,)
    const float* __restrict__ W1,     // (INF, H1)
    const float* __restrict__ b1,     // (H1,)
    const float* __restrict__ W2,     // (H1, H2)
    const float* __restrict__ b2,     // (H2,)
    const float* __restrict__ W3,     // (H2, H3)
    const float* __restrict__ b3,     // (H3,)
    float* __restrict__ out)          // (H3, NPT)
{
    __shared__ __align__(16) float smem[LTOT];

    // ---- cooperative stage of all weights into LDS
    {
        const int tid = threadIdx.x;
        for (int i = tid; i < INF*H1; i += 256) smem[LW1 + i] = W1[i];
        for (int i = tid; i < H1*H2;  i += 256) smem[LW2 + i] = W2[i];
        if (tid < H1)  smem[LB1 + tid] = b1[tid];
        if (tid < H2)  smem[LB2 + tid] = b2[tid];
        if (tid < H2*H3) smem[LW3 + tid] = W3[tid];
        if (tid < H3)  smem[LB3 + tid] = b3[tid];
    }
    __syncthreads();

    const int t    = blockIdx.x * 256 + threadIdx.x;
    const int pt   = t >> 1;          // point index
    const int half = t & 1;           // which 5-neighbor half

    float fr[MF];
    #pragma unroll
    for (int m = 0; m < MF; ++m) fr[m] = freqs[m];

    float acc[H3];
    #pragma unroll
    for (int c = 0; c < H3; ++c) acc[c] = 0.0f;

    const float4* W1v = (const float4*)(smem + LW1);  // [33][16]
    const float4* B1v = (const float4*)(smem + LB1);  // [16]
    const float4* W2v = (const float4*)(smem + LW2);  // [64][8]
    const float4* B2v = (const float4*)(smem + LB2);  // [8]
    const float4* W3v = (const float4*)(smem + LW3);  // [32][2]
    const float4* B3v = (const float4*)(smem + LB3);  // [2]

    const int p0 = half * 5;
    #pragma unroll 1
    for (int pp = 0; pp < 5; ++pp) {
        const int p = p0 + pp;
        const float* xp = x + ((long)pt * PN + p) * 3;
        const float cx = xp[0], cy = xp[1], cz = xp[2];

        // ---- Fourier features: [x(3), sin(15), cos(15)]; sin/cos index m*3+d
        float feat[INF];
        feat[0] = cx; feat[1] = cy; feat[2] = cz;
        #pragma unroll
        for (int m = 0; m < MF; ++m) {
            float s, c;
            __sincosf(cx * fr[m], &s, &c); feat[3 + m*3 + 0] = s; feat[18 + m*3 + 0] = c;
            __sincosf(cy * fr[m], &s, &c); feat[3 + m*3 + 1] = s; feat[18 + m*3 + 1] = c;
            __sincosf(cz * fr[m], &s, &c); feat[3 + m*3 + 2] = s; feat[18 + m*3 + 2] = c;
        }

        // ---- Layer 1: 33 -> 64, exact GELU  (weights via ds_read_b128 broadcast)
        float h1[H1];
        #pragma unroll
        for (int j = 0; j < H1/4; ++j) {
            const float4 b = B1v[j];
            h1[j*4+0] = b.x; h1[j*4+1] = b.y; h1[j*4+2] = b.z; h1[j*4+3] = b.w;
        }
        #pragma unroll
        for (int i = 0; i < INF; ++i) {
            const float f = feat[i];
            #pragma unroll
            for (int j = 0; j < H1/4; ++j) {
                const float4 w = W1v[i*(H1/4) + j];
                h1[j*4+0] += f * w.x;
                h1[j*4+1] += f * w.y;
                h1[j*4+2] += f * w.z;
                h1[j*4+3] += f * w.w;
            }
        }
        #pragma unroll
        for (int j = 0; j < H1; ++j) h1[j] = gelu_exact(h1[j]);

        // ---- Layer 2: 64 -> 32, exact GELU
        float h2[H2];
        #pragma unroll
        for (int j = 0; j < H2/4; ++j) {
            const float4 b = B2v[j];
            h2[j*4+0] = b.x; h2[j*4+1] = b.y; h2[j*4+2] = b.z; h2[j*4+3] = b.w;
        }
        #pragma unroll
        for (int i = 0; i < H1; ++i) {
            const float f = h1[i];
            #pragma unroll
            for (int j = 0; j < H2/4; ++j) {
                const float4 w = W2v[i*(H2/4) + j];
                h2[j*4+0] += f * w.x;
                h2[j*4+1] += f * w.y;
                h2[j*4+2] += f * w.z;
                h2[j*4+3] += f * w.w;
            }
        }
        #pragma unroll
        for (int j = 0; j < H2; ++j) h2[j] = gelu_exact(h2[j]);

        // ---- Layer 3: 32 -> 8, tanh; mask on |x-coord| > 1e-6
        float h3[H3];
        #pragma unroll
        for (int j = 0; j < H3/4; ++j) {
            const float4 b = B3v[j];
            h3[j*4+0] = b.x; h3[j*4+1] = b.y; h3[j*4+2] = b.z; h3[j*4+3] = b.w;
        }
        #pragma unroll
        for (int i = 0; i < H2; ++i) {
            const float f = h2[i];
            #pragma unroll
            for (int j = 0; j < H3/4; ++j) {
                const float4 w = W3v[i*(H3/4) + j];
                h3[j*4+0] += f * w.x;
                h3[j*4+1] += f * w.y;
                h3[j*4+2] += f * w.z;
                h3[j*4+3] += f * w.w;
            }
        }
        const float mk = (fabsf(cx) > 1e-6f) ? 1.0f : 0.0f;
        #pragma unroll
        for (int c = 0; c < H3; ++c) acc[c] += mk * tanhf(h3[c]);
    }

    // ---- pair reduction (threads 2k, 2k+1 are adjacent lanes in one wave)
    #pragma unroll
    for (int c = 0; c < H3; ++c) {
        acc[c] += __shfl_xor(acc[c], 1, 64);
    }
    if (half == 0) {
        #pragma unroll
        for (int c = 0; c < H3; ++c) out[(long)c * NPT + pt] = acc[c];
    }
}

extern "C" void kernel_launch(void* const* d_in, const int* in_sizes, int n_in,
                              void* d_out, int out_size, void* d_ws, size_t ws_size,
                              hipStream_t stream) {
    // setup_inputs order: x, grid(unused), freqs, W1, b1, W2, b2, W3, b3
    const float* x     = (const float*)d_in[0];
    const float* freqs = (const float*)d_in[2];
    const float* W1    = (const float*)d_in[3];
    const float* b1    = (const float*)d_in[4];
    const float* W2    = (const float*)d_in[5];
    const float* b2    = (const float*)d_in[6];
    const float* W3    = (const float*)d_in[7];
    const float* b3    = (const float*)d_in[8];
    float* out = (float*)d_out;

    const int threads = NPT * 2;           // 196608
    const int block   = 256;
    const int grid    = (threads + block - 1) / block;  // 768
    domino_mlp_kernel<<<grid, block, 0, stream>>>(x, freqs, W1, b1, W2, b2, W3, b3, out);
}

// Round 3
// 144.810 us; speedup vs baseline: 144.0175x; 144.0175x over previous
//
#include <hip/hip_runtime.h>
#include <math.h>

// Problem constants
#define NXD 64
#define NYD 48
#define NZD 32
#define NPT (NXD*NYD*NZD)   // 98304 points
#define PN  10              // neighbors per point
#define MF  5               // fourier modes
#define H1  64
#define H2  32
#define H3  8

// Block geometry: 256 threads = 4 waves; 32 points = 320 rows per block;
// each wave owns 8 points = 80 rows = 5 tiles of 16 rows.
#define PTS_PER_BLOCK 32
#define ROWS_PER_BLOCK (PTS_PER_BLOCK*PN)   // 320
#define TILES_PER_WAVE 5

// LDS strides (bf16 elements) — keep row stride a multiple of 8 (16B) for b128
#define A2S 72   // 16 rows x 72 (64 ch + pad)
#define A3S 40   // 16 rows x 40 (32 ch + pad)

typedef __attribute__((ext_vector_type(8))) short short8;  // 8 bf16 = 4 VGPRs
typedef __attribute__((ext_vector_type(4))) float f32x4;

__device__ __forceinline__ short f2bf(float f) {
    // round-to-nearest-even fp32 -> bf16 (values here are bounded, no NaN/Inf)
    unsigned u = __float_as_uint(f);
    unsigned r = (u + 0x7fffu + ((u >> 16) & 1u)) >> 16;
    return (short)r;
}

__device__ __forceinline__ float gelu_exact(float v) {
    return 0.5f * v * (1.0f + erff(v * 0.70710678118654752f));
}

__global__ __launch_bounds__(256) void domino_mfma_kernel(
    const float* __restrict__ x,      // (NPT*PN, 3)
    const float* __restrict__ freqs,  // (MF,)
    const float* __restrict__ W1,     // (33, 64)
    const float* __restrict__ b1,
    const float* __restrict__ W2,     // (64, 32)
    const float* __restrict__ b2,
    const float* __restrict__ W3,     // (32, 8)
    const float* __restrict__ b3,
    float* __restrict__ out)          // (8, NPT)
{
    __shared__ float obuf[ROWS_PER_BLOCK * 9];                  // masked tanh rows, stride 9 vs bank aliasing
    __shared__ __align__(16) unsigned short a2buf[4][16 * A2S]; // per-wave L1->L2 transpose
    __shared__ __align__(16) unsigned short a3buf[4][16 * A3S]; // per-wave L2->L3 transpose
    __shared__ float mcx[4][16];   // x-coordinate per row (mask)
    __shared__ float mv32[4][16];  // feature ch32 = cos(f4*z) per row

    const int tid  = threadIdx.x;
    const int w    = tid >> 6;      // wave id 0..3
    const int lane = tid & 63;
    const int lr   = lane & 15;     // A-row / B-col / C-col index
    const int lg   = lane >> 4;     // k-group / C-row-group

    // ---- frequencies
    float fr[MF];
    #pragma unroll
    for (int m = 0; m < MF; ++m) fr[m] = freqs[m];

    // ---- preload weight fragments (once per wave; lanes hold their B-frag slices)
    // B layout for 16x16x32: n = lane&15, k = (lane>>4)*8 + j
    short8 B1f[4];                      // layer1: K=32 (ch0..31), N=64 -> 4 n-tiles
    float  w32[4], bv1[4];              // ch32 rank-1 fixup weights + bias
    #pragma unroll
    for (int t1 = 0; t1 < 4; ++t1) {
        #pragma unroll
        for (int j = 0; j < 8; ++j)
            B1f[t1][j] = f2bf(W1[(lg*8 + j)*H1 + t1*16 + lr]);
        w32[t1] = W1[32*H1 + t1*16 + lr];
        bv1[t1] = b1[t1*16 + lr];
    }
    short8 B2f[2][2];                   // layer2: K=64 (2 steps), N=32 -> 2 n-tiles
    float  bv2[2];
    #pragma unroll
    for (int s = 0; s < 2; ++s)
        #pragma unroll
        for (int t2 = 0; t2 < 2; ++t2)
            #pragma unroll
            for (int j = 0; j < 8; ++j)
                B2f[s][t2][j] = f2bf(W2[(s*32 + lg*8 + j)*H2 + t2*16 + lr]);
    #pragma unroll
    for (int t2 = 0; t2 < 2; ++t2) bv2[t2] = b2[t2*16 + lr];

    short8 B3f;                         // layer3: K=32, N=16 (cols 8..15 zero)
    float  bv3 = (lr < H3) ? b3[lr] : 0.0f;
    #pragma unroll
    for (int j = 0; j < 8; ++j)
        B3f[j] = (lr < H3) ? f2bf(W3[(lg*8 + j)*H3 + lr]) : (short)0;

    const int wrow0 = blockIdx.x * ROWS_PER_BLOCK + w * (TILES_PER_WAVE*16);

    #pragma unroll 1
    for (int t = 0; t < TILES_PER_WAVE; ++t) {
        const int row0  = wrow0 + t*16;
        const int myrow = row0 + lr;          // the A-row this lane generates

        // ---- load coords (lanes in 4 groups read the same 12B; L1 broadcast)
        const float* xp = x + (size_t)myrow * 3;
        const float cx = xp[0], cy = xp[1], cz = xp[2];

        // ---- all sin/cos: index m*3+d
        float sv[15], cv[15];
        #pragma unroll
        for (int m = 0; m < MF; ++m) {
            __sincosf(fr[m]*cx, &sv[m*3+0], &cv[m*3+0]);
            __sincosf(fr[m]*cy, &sv[m*3+1], &cv[m*3+1]);
            __sincosf(fr[m]*cz, &sv[m*3+2], &cv[m*3+2]);
        }

        // stage per-row mask coord and feature ch32 = cv[14]
        if (lg == 0) { mcx[w][lr] = cx; mv32[w][lr] = cv[14]; }

        // ---- select this lane's 8 feature channels k = lg*8 .. lg*8+7
        // feat: [cx,cy,cz, sv0..sv14, cv0..cv14] (ch32=cv14 via fixup)
        float fv[8];
        if (lg == 0) {
            fv[0]=cx; fv[1]=cy; fv[2]=cz;
            fv[3]=sv[0]; fv[4]=sv[1]; fv[5]=sv[2]; fv[6]=sv[3]; fv[7]=sv[4];
        } else if (lg == 1) {
            fv[0]=sv[5];  fv[1]=sv[6];  fv[2]=sv[7];  fv[3]=sv[8];
            fv[4]=sv[9];  fv[5]=sv[10]; fv[6]=sv[11]; fv[7]=sv[12];
        } else if (lg == 2) {
            fv[0]=sv[13]; fv[1]=sv[14]; fv[2]=cv[0];  fv[3]=cv[1];
            fv[4]=cv[2];  fv[5]=cv[3];  fv[6]=cv[4];  fv[7]=cv[5];
        } else {
            fv[0]=cv[6];  fv[1]=cv[7];  fv[2]=cv[8];  fv[3]=cv[9];
            fv[4]=cv[10]; fv[5]=cv[11]; fv[6]=cv[12]; fv[7]=cv[13];
        }
        short8 a1;
        #pragma unroll
        for (int j = 0; j < 8; ++j) a1[j] = f2bf(fv[j]);

        // ---- Layer 1: 4 n-tiles, K=32, bias-initialized accumulators
        f32x4 c1[4];
        #pragma unroll
        for (int t1 = 0; t1 < 4; ++t1) {
            f32x4 ci = {bv1[t1], bv1[t1], bv1[t1], bv1[t1]};
            c1[t1] = __builtin_amdgcn_mfma_f32_16x16x32_bf16(a1, B1f[t1], ci, 0, 0, 0);
        }
        // ch32 rank-1 fixup + mask coords for this lane's 4 C-rows
        float v32r[4], mxr[4];
        #pragma unroll
        for (int r = 0; r < 4; ++r) { v32r[r] = mv32[w][lg*4 + r]; mxr[r] = mcx[w][lg*4 + r]; }
        #pragma unroll
        for (int t1 = 0; t1 < 4; ++t1)
            #pragma unroll
            for (int r = 0; r < 4; ++r)
                c1[t1][r] += v32r[r] * w32[t1];
        // GELU
        #pragma unroll
        for (int t1 = 0; t1 < 4; ++t1)
            #pragma unroll
            for (int r = 0; r < 4; ++r)
                c1[t1][r] = gelu_exact(c1[t1][r]);

        // ---- transpose L1 out (C-layout) -> A-layout via LDS
        #pragma unroll
        for (int t1 = 0; t1 < 4; ++t1)
            #pragma unroll
            for (int r = 0; r < 4; ++r)
                a2buf[w][(lg*4 + r)*A2S + t1*16 + lr] = (unsigned short)f2bf(c1[t1][r]);
        short8 a2f[2];
        #pragma unroll
        for (int s = 0; s < 2; ++s)
            a2f[s] = *(const short8*)&a2buf[w][lr*A2S + s*32 + lg*8];

        // ---- Layer 2: K=64 (2 steps), 2 n-tiles
        f32x4 c2[2];
        #pragma unroll
        for (int t2 = 0; t2 < 2; ++t2) {
            f32x4 ci = {bv2[t2], bv2[t2], bv2[t2], bv2[t2]};
            ci = __builtin_amdgcn_mfma_f32_16x16x32_bf16(a2f[0], B2f[0][t2], ci, 0, 0, 0);
            c2[t2] = __builtin_amdgcn_mfma_f32_16x16x32_bf16(a2f[1], B2f[1][t2], ci, 0, 0, 0);
        }
        #pragma unroll
        for (int t2 = 0; t2 < 2; ++t2)
            #pragma unroll
            for (int r = 0; r < 4; ++r)
                c2[t2][r] = gelu_exact(c2[t2][r]);

        // ---- transpose L2 out -> A-layout
        #pragma unroll
        for (int t2 = 0; t2 < 2; ++t2)
            #pragma unroll
            for (int r = 0; r < 4; ++r)
                a3buf[w][(lg*4 + r)*A3S + t2*16 + lr] = (unsigned short)f2bf(c2[t2][r]);
        short8 a3f = *(const short8*)&a3buf[w][lr*A3S + lg*8];

        // ---- Layer 3: K=32, N=16 (8 valid)
        f32x4 c3 = {bv3, bv3, bv3, bv3};
        c3 = __builtin_amdgcn_mfma_f32_16x16x32_bf16(a3f, B3f, c3, 0, 0, 0);

        // ---- tanh, mask, store per-row result to block buffer
        #pragma unroll
        for (int r = 0; r < 4; ++r) {
            const int brow = w*(TILES_PER_WAVE*16) + t*16 + lg*4 + r;
            const float mk = (fabsf(mxr[r]) > 1e-6f) ? 1.0f : 0.0f;
            if (lr < H3) obuf[brow*9 + lr] = mk * tanhf(c3[r]);
        }
    }

    __syncthreads();

    // ---- neighbor reduction: 32 points x 8 channels = 256 threads
    {
        const int p  = tid >> 3;   // 0..31
        const int ch = tid & 7;
        float sum = 0.0f;
        #pragma unroll
        for (int i = 0; i < PN; ++i) sum += obuf[(p*PN + i)*9 + ch];
        const int gp = blockIdx.x * PTS_PER_BLOCK + p;
        out[(size_t)ch * NPT + gp] = sum;
    }
}

extern "C" void kernel_launch(void* const* d_in, const int* in_sizes, int n_in,
                              void* d_out, int out_size, void* d_ws, size_t ws_size,
                              hipStream_t stream) {
    // setup_inputs order: x, grid(unused), freqs, W1, b1, W2, b2, W3, b3
    const float* x     = (const float*)d_in[0];
    const float* freqs = (const float*)d_in[2];
    const float* W1    = (const float*)d_in[3];
    const float* b1    = (const float*)d_in[4];
    const float* W2    = (const float*)d_in[5];
    const float* b2    = (const float*)d_in[6];
    const float* W3    = (const float*)d_in[7];
    const float* b3    = (const float*)d_in[8];
    float* out = (float*)d_out;

    const int grid = NPT / PTS_PER_BLOCK;   // 3072 blocks, no remainder
    domino_mfma_kernel<<<grid, 256, 0, stream>>>(x, freqs, W1, b1, W2, b2, W3, b3, out);
}

// Round 4
// 127.577 us; speedup vs baseline: 163.4715x; 1.1351x over previous
//
#include <hip/hip_runtime.h>
#include <math.h>

// Problem constants
#define NXD 64
#define NYD 48
#define NZD 32
#define NPT (NXD*NYD*NZD)   // 98304 points
#define PN  10              // neighbors per point
#define MF  5               // fourier modes
#define H1  64
#define H2  32
#define H3  8

// Block geometry: 256 threads = 4 waves; 32 points = 320 rows per block;
// each wave owns 8 points = 80 rows = 5 tiles of 16 rows.
#define PTS_PER_BLOCK 32
#define ROWS_PER_BLOCK (PTS_PER_BLOCK*PN)   // 320
#define TILES_PER_WAVE 5

// LDS strides (bf16 elements) — row stride multiple of 8 (16B) for ds_read_b128
#define A2S 72   // 16 rows x 72 (64 ch + pad)
#define A3S 40   // 16 rows x 40 (32 ch + pad)

typedef __attribute__((ext_vector_type(8))) short short8;  // 8 bf16 = 4 VGPRs
typedef __attribute__((ext_vector_type(4))) float f32x4;

// exact RNE fp32->bf16 (used only for one-time weight conversion)
__device__ __forceinline__ short f2bf(float f) {
    unsigned u = __float_as_uint(f);
    unsigned r = (u + 0x7fffu + ((u >> 16) & 1u)) >> 16;
    return (short)r;
}

// fast fp32->bf16, round-to-nearest (half-up on exact ties): 2 VALU
__device__ __forceinline__ unsigned short f2bf_hu(float f) {
    return (unsigned short)((__float_as_uint(f) + 0x8000u) >> 16);
}

// pack two fp32 -> one dword of 2 bf16 (lo in low half): 2 adds + v_perm
__device__ __forceinline__ unsigned pack2_bf16(float lo, float hi) {
    return __builtin_amdgcn_perm(__float_as_uint(hi) + 0x8000u,
                                 __float_as_uint(lo) + 0x8000u, 0x07060302u);
}

// tanh-form GELU via hw exp+rcp: gelu = x - x/(1+e^{2u}), 2u = 1.5957691(x+0.044715x^3)
// approx error vs exact erf-gelu ~3e-4; saturates correctly (rcp(inf)=0, exp(-inf)=0)
__device__ __forceinline__ float gelu_fast(float x) {
    float x2 = x * x;
    float t  = x * (1.59576912f + 0.07135482f * x2);
    float E  = __expf(t);                       // v_mul(log2e) + v_exp_f32
    return x - x * __builtin_amdgcn_rcpf(E + 1.0f);
}

// tanh via hw exp+rcp: 1 - 2/(1+e^{2v}); safe at both infinities
__device__ __forceinline__ float tanh_fast(float v) {
    float E = __expf(2.0f * v);
    return 1.0f - 2.0f * __builtin_amdgcn_rcpf(E + 1.0f);
}

__global__ __launch_bounds__(256) void domino_mfma_kernel(
    const float* __restrict__ x,      // (NPT*PN, 3)
    const float* __restrict__ freqs,  // (MF,)
    const float* __restrict__ W1,     // (33, 64)
    const float* __restrict__ b1,
    const float* __restrict__ W2,     // (64, 32)
    const float* __restrict__ b2,
    const float* __restrict__ W3,     // (32, 8)
    const float* __restrict__ b3,
    float* __restrict__ out)          // (8, NPT)
{
    __shared__ float obuf[ROWS_PER_BLOCK * 9];                  // masked tanh rows
    __shared__ __align__(16) unsigned short a2buf[4][16 * A2S]; // per-wave L1->L2 transpose
    __shared__ __align__(16) unsigned short a3buf[4][16 * A3S]; // per-wave L2->L3 transpose
    __shared__ __align__(16) float mcx[4][16];   // x-coordinate per row (mask)
    __shared__ __align__(16) float mv32[4][16];  // feature ch32 = cos(f4*z) per row

    const int tid  = threadIdx.x;
    const int w    = tid >> 6;      // wave id 0..3
    const int lane = tid & 63;
    const int lr   = lane & 15;     // A-row / B-col / C-col index
    const int lg   = lane >> 4;     // k-group / C-row-group

    // ---- frequencies
    float fr[MF];
    #pragma unroll
    for (int m = 0; m < MF; ++m) fr[m] = freqs[m];

    // ---- preload weight fragments (once per wave)
    // B layout for 16x16x32: n = lane&15, k = (lane>>4)*8 + j
    short8 B1f[4];                      // layer1: K=32 (ch0..31), N=64 -> 4 n-tiles
    float  w32[4], bv1[4];              // ch32 rank-1 fixup weights + bias
    #pragma unroll
    for (int t1 = 0; t1 < 4; ++t1) {
        #pragma unroll
        for (int j = 0; j < 8; ++j)
            B1f[t1][j] = f2bf(W1[(lg*8 + j)*H1 + t1*16 + lr]);
        w32[t1] = W1[32*H1 + t1*16 + lr];
        bv1[t1] = b1[t1*16 + lr];
    }
    short8 B2f[2][2];                   // layer2: K=64 (2 steps), N=32 -> 2 n-tiles
    float  bv2[2];
    #pragma unroll
    for (int s = 0; s < 2; ++s)
        #pragma unroll
        for (int t2 = 0; t2 < 2; ++t2)
            #pragma unroll
            for (int j = 0; j < 8; ++j)
                B2f[s][t2][j] = f2bf(W2[(s*32 + lg*8 + j)*H2 + t2*16 + lr]);
    #pragma unroll
    for (int t2 = 0; t2 < 2; ++t2) bv2[t2] = b2[t2*16 + lr];

    short8 B3f;                         // layer3: K=32, N=16 (cols 8..15 zero)
    float  bv3 = (lr < H3) ? b3[lr] : 0.0f;
    #pragma unroll
    for (int j = 0; j < 8; ++j)
        B3f[j] = (lr < H3) ? f2bf(W3[(lg*8 + j)*H3 + lr]) : (short)0;

    const int wrow0 = blockIdx.x * ROWS_PER_BLOCK + w * (TILES_PER_WAVE*16);

    #pragma unroll 1
    for (int t = 0; t < TILES_PER_WAVE; ++t) {
        const int myrow = wrow0 + t*16 + lr;  // the A-row this lane generates

        // ---- load coords (4 lane-groups read the same 12B; L1 broadcast)
        const float* xp = x + (size_t)myrow * 3;
        const float cx = xp[0], cy = xp[1], cz = xp[2];

        // ---- all sin/cos: index m*3+d
        float sv[15], cv[15];
        #pragma unroll
        for (int m = 0; m < MF; ++m) {
            __sincosf(fr[m]*cx, &sv[m*3+0], &cv[m*3+0]);
            __sincosf(fr[m]*cy, &sv[m*3+1], &cv[m*3+1]);
            __sincosf(fr[m]*cz, &sv[m*3+2], &cv[m*3+2]);
        }

        // stage per-row mask coord and feature ch32 = cv[14]
        if (lg == 0) { mcx[w][lr] = cx; mv32[w][lr] = cv[14]; }

        // ---- select this lane's 8 feature channels k = lg*8 .. lg*8+7
        float fv[8];
        if (lg == 0) {
            fv[0]=cx; fv[1]=cy; fv[2]=cz;
            fv[3]=sv[0]; fv[4]=sv[1]; fv[5]=sv[2]; fv[6]=sv[3]; fv[7]=sv[4];
        } else if (lg == 1) {
            fv[0]=sv[5];  fv[1]=sv[6];  fv[2]=sv[7];  fv[3]=sv[8];
            fv[4]=sv[9];  fv[5]=sv[10]; fv[6]=sv[11]; fv[7]=sv[12];
        } else if (lg == 2) {
            fv[0]=sv[13]; fv[1]=sv[14]; fv[2]=cv[0];  fv[3]=cv[1];
            fv[4]=cv[2];  fv[5]=cv[3];  fv[6]=cv[4];  fv[7]=cv[5];
        } else {
            fv[0]=cv[6];  fv[1]=cv[7];  fv[2]=cv[8];  fv[3]=cv[9];
            fv[4]=cv[10]; fv[5]=cv[11]; fv[6]=cv[12]; fv[7]=cv[13];
        }
        union { unsigned u[4]; short8 s8; } a1u;
        #pragma unroll
        for (int j = 0; j < 4; ++j) a1u.u[j] = pack2_bf16(fv[2*j], fv[2*j+1]);
        const short8 a1 = a1u.s8;

        // ---- Layer 1: 4 n-tiles, K=32, bias-initialized accumulators
        f32x4 c1[4];
        #pragma unroll
        for (int t1 = 0; t1 < 4; ++t1) {
            f32x4 ci = {bv1[t1], bv1[t1], bv1[t1], bv1[t1]};
            c1[t1] = __builtin_amdgcn_mfma_f32_16x16x32_bf16(a1, B1f[t1], ci, 0, 0, 0);
        }
        // ch32 rank-1 fixup + mask coords for this lane's 4 C-rows (float4 LDS reads)
        const f32x4 v32r = *(const f32x4*)&mv32[w][lg*4];
        const f32x4 mxr  = *(const f32x4*)&mcx[w][lg*4];
        #pragma unroll
        for (int t1 = 0; t1 < 4; ++t1)
            #pragma unroll
            for (int r = 0; r < 4; ++r)
                c1[t1][r] += v32r[r] * w32[t1];
        #pragma unroll
        for (int t1 = 0; t1 < 4; ++t1)
            #pragma unroll
            for (int r = 0; r < 4; ++r)
                c1[t1][r] = gelu_fast(c1[t1][r]);

        // ---- transpose L1 out (C-layout) -> A-layout via LDS
        #pragma unroll
        for (int t1 = 0; t1 < 4; ++t1)
            #pragma unroll
            for (int r = 0; r < 4; ++r)
                a2buf[w][(lg*4 + r)*A2S + t1*16 + lr] = f2bf_hu(c1[t1][r]);
        short8 a2f[2];
        #pragma unroll
        for (int s = 0; s < 2; ++s)
            a2f[s] = *(const short8*)&a2buf[w][lr*A2S + s*32 + lg*8];

        // ---- Layer 2: K=64 (2 steps), 2 n-tiles
        f32x4 c2[2];
        #pragma unroll
        for (int t2 = 0; t2 < 2; ++t2) {
            f32x4 ci = {bv2[t2], bv2[t2], bv2[t2], bv2[t2]};
            ci = __builtin_amdgcn_mfma_f32_16x16x32_bf16(a2f[0], B2f[0][t2], ci, 0, 0, 0);
            c2[t2] = __builtin_amdgcn_mfma_f32_16x16x32_bf16(a2f[1], B2f[1][t2], ci, 0, 0, 0);
        }
        #pragma unroll
        for (int t2 = 0; t2 < 2; ++t2)
            #pragma unroll
            for (int r = 0; r < 4; ++r)
                c2[t2][r] = gelu_fast(c2[t2][r]);

        // ---- transpose L2 out -> A-layout
        #pragma unroll
        for (int t2 = 0; t2 < 2; ++t2)
            #pragma unroll
            for (int r = 0; r < 4; ++r)
                a3buf[w][(lg*4 + r)*A3S + t2*16 + lr] = f2bf_hu(c2[t2][r]);
        short8 a3f = *(const short8*)&a3buf[w][lr*A3S + lg*8];

        // ---- Layer 3: K=32, N=16 (8 valid)
        f32x4 c3 = {bv3, bv3, bv3, bv3};
        c3 = __builtin_amdgcn_mfma_f32_16x16x32_bf16(a3f, B3f, c3, 0, 0, 0);

        // ---- tanh, mask, store per-row result to block buffer
        #pragma unroll
        for (int r = 0; r < 4; ++r) {
            const int brow = w*(TILES_PER_WAVE*16) + t*16 + lg*4 + r;
            const float mk = (fabsf(mxr[r]) > 1e-6f) ? 1.0f : 0.0f;
            if (lr < H3) obuf[brow*9 + lr] = mk * tanh_fast(c3[r]);
        }
    }

    __syncthreads();

    // ---- neighbor reduction: 32 points x 8 channels = 256 threads
    {
        const int p  = tid >> 3;   // 0..31
        const int ch = tid & 7;
        float sum = 0.0f;
        #pragma unroll
        for (int i = 0; i < PN; ++i) sum += obuf[(p*PN + i)*9 + ch];
        const int gp = blockIdx.x * PTS_PER_BLOCK + p;
        out[(size_t)ch * NPT + gp] = sum;
    }
}

extern "C" void kernel_launch(void* const* d_in, const int* in_sizes, int n_in,
                              void* d_out, int out_size, void* d_ws, size_t ws_size,
                              hipStream_t stream) {
    // setup_inputs order: x, grid(unused), freqs, W1, b1, W2, b2, W3, b3
    const float* x     = (const float*)d_in[0];
    const float* freqs = (const float*)d_in[2];
    const float* W1    = (const float*)d_in[3];
    const float* b1    = (const float*)d_in[4];
    const float* W2    = (const float*)d_in[5];
    const float* b2    = (const float*)d_in[6];
    const float* W3    = (const float*)d_in[7];
    const float* b3    = (const float*)d_in[8];
    float* out = (float*)d_out;

    const int grid = NPT / PTS_PER_BLOCK;   // 3072 blocks, no remainder
    domino_mfma_kernel<<<grid, 256, 0, stream>>>(x, freqs, W1, b1, W2, b2, W3, b3, out);
}